// Round 3
// baseline (607.617 us; speedup 1.0000x reference)
//
#include <hip/hip_runtime.h>
#include <cstdint>

typedef unsigned short u16;
typedef unsigned short ushortx8 __attribute__((ext_vector_type(8)));
typedef __bf16 bf16x8 __attribute__((ext_vector_type(8)));
typedef float f32x4 __attribute__((ext_vector_type(4)));

// Problem constants
#define B_    16
#define CIN   512
#define COUT  512
#define HW_   64
#define PW    66            // padded width/height
#define XH_ELEMS ((size_t)B_*PW*PW*CIN)              // 35,684,352 u16 (71.4 MB)
#define WA_ELEMS ((size_t)B_*16*9*COUT*32)           // 37,748,736 u16 (75.5 MB)

__device__ __forceinline__ float bf2f(u16 v) {
  union { unsigned int u; float f; } c; c.u = ((unsigned int)v) << 16; return c.f;
}
__device__ __forceinline__ u16 f2bf(float f) {
  union { float f; unsigned int u; } c; c.f = f;
  unsigned int u = c.u + 0x7fffu + ((c.u >> 16) & 1u);   // RNE
  return (u16)(u >> 16);
}

// async global->LDS, 16B per lane; dest must be wave-uniform-base + lane*16
__device__ __forceinline__ void async16(const void* g, void* l) {
  __builtin_amdgcn_global_load_lds(
      (__attribute__((address_space(1))) unsigned int*)(uintptr_t)g,
      (__attribute__((address_space(3))) unsigned int*)(uintptr_t)l,
      16, 0, 0);
}

// ---------------------------------------------------------------------------
// Kernel 1: zero the padding border of xh[b][66][66][512]
// 16 b * 260 border pixels * 512 ch -> as ushort8: 16*260*64 = 266,240 threads
__global__ __launch_bounds__(256) void zero_border(u16* __restrict__ xh) {
  int g = blockIdx.x * 256 + threadIdx.x;
  if (g >= B_ * 260 * 64) return;
  int c8 = g & 63;
  int t  = g >> 6;             // 0 .. 16*260-1
  int b  = t / 260;
  int p  = t - b * 260;
  int rp, cp;
  if (p < 66)       { rp = 0;      cp = p; }
  else if (p < 132) { rp = 65;     cp = p - 66; }
  else {
    int q = p - 132;           // 0..127
    if (q < 64) { rp = q + 1;  cp = 0; }
    else        { rp = q - 63; cp = 65; }
  }
  u16* dst = xh + ((((size_t)b * PW + rp) * PW + cp) << 9) + (c8 << 3);
  *(uint4*)dst = make_uint4(0u, 0u, 0u, 0u);
}

// ---------------------------------------------------------------------------
// Kernel 2: fp32 NCHW -> bf16 padded NHWC transpose
// xh[b][y+1][x+1][i] = bf16(x[b][i][y][x]).  grid (ichunk=8, y=64, b=16).
__global__ __launch_bounds__(256) void transpose_x(const float* __restrict__ x,
                                                   u16* __restrict__ xh) {
  __shared__ u16 tile[64][72];   // [ci][x], +8 pad
  const int b  = blockIdx.z;
  const int y  = blockIdx.y;
  const int i0 = blockIdx.x * 64;
  const int t  = threadIdx.x;

  // load phase: 64 ci x 64 x floats, float4-vectorized along x, cvt to bf16
  const int ciL = t >> 4;            // 0..15
  const int xg  = (t & 15) * 4;      // 0,4,...,60
#pragma unroll
  for (int u = 0; u < 4; ++u) {
    const int ci = ciL + u * 16;
    const float4 v = *(const float4*)(
        x + ((((size_t)b * CIN + i0 + ci) * HW_ + y) * HW_ + xg));
    u16* d = &tile[ci][xg];
    d[0] = f2bf(v.x); d[1] = f2bf(v.y); d[2] = f2bf(v.z); d[3] = f2bf(v.w);
  }
  __syncthreads();

  // store phase: consecutive channels contiguous in global
  const int xx = t >> 2;             // 0..63
  const int cg = (t & 3) * 16;       // ci group of 16
  u16 outv[16];
#pragma unroll
  for (int u = 0; u < 16; ++u) outv[u] = tile[cg + u][xx];
  u16* dst = xh + ((((size_t)b * PW + (y + 1)) * PW + (xx + 1)) << 9) + i0 + cg;
  *(uint4*)dst       = *(uint4*)&outv[0];
  *(uint4*)(dst + 8) = *(uint4*)&outv[8];
}

// ---------------------------------------------------------------------------
// Kernel 3: modulate + demodulate weights (fp32 in), write bf16 MFMA layout
// wA[b][ic=i/32][tap][o][i%32] bf16.  One wave per (b,o): 8192 waves.
__global__ __launch_bounds__(256) void mod_weights(const float* __restrict__ w,
                                                   const float* __restrict__ s,
                                                   u16* __restrict__ wA) {
  const int gwid = (blockIdx.x * 256 + threadIdx.x) >> 6;  // 0..8191
  const int lane = threadIdx.x & 63;
  const int b = gwid >> 9;
  const int o = gwid & 511;
  const float* wrow = w + (size_t)o * (CIN * 9);
  const float* srow = s + (size_t)b * CIN;

  float acc = 0.f;
  float sv[8];
#pragma unroll
  for (int j = 0; j < 8; ++j) {
    const int i = lane + j * 64;
    const float si = srow[i];
    sv[j] = si;
    const float* wp = wrow + i * 9;
    float q = 0.f;
#pragma unroll
    for (int t = 0; t < 9; ++t) { float wv = wp[t]; q += wv * wv; }
    acc += si * si * q;
  }
#pragma unroll
  for (int off = 32; off > 0; off >>= 1) acc += __shfl_xor(acc, off, 64);

  const float C_EQ = 1.4731391e-2f;                 // 1/sqrt(512*9)
  const float sigma_inv = rsqrtf(acc * (C_EQ * C_EQ) + 1e-8f);

  u16* base = wA + (size_t)b * (16 * 9 * COUT * 32);
#pragma unroll
  for (int j = 0; j < 8; ++j) {
    const int i = lane + j * 64;
    const float scale = C_EQ * sv[j] * sigma_inv;
    const float* wp = wrow + i * 9;
    const int icc = i >> 5, ich = i & 31;
#pragma unroll
    for (int t = 0; t < 9; ++t) {
      base[(((icc * 9 + t) * COUT) + o) * 32 + ich] = f2bf(wp[t] * scale);
    }
  }
}

// ---------------------------------------------------------------------------
// Kernel 4: implicit-GEMM conv.  Block = 128 o x 128 pix (2 rows), 4 waves.
// K-loop: 16 chunks of 32 channels; input window (4 rows x 66 cols x 32 ch)
// staged once per chunk, reused by all 9 taps; A tile (128x32) staged per tap.
__global__ __launch_bounds__(256) void modconv_mfma(const u16* __restrict__ xh,
                                                    const u16* __restrict__ wA,
                                                    const float* __restrict__ bias,
                                                    float* __restrict__ out) {
  __shared__ u16 As[128 * 32];        // [o_local][ch]          8 KB
  __shared__ u16 Bs[264 * 32];        // [r*66+c][ch]          16.9 KB

  const int tid  = threadIdx.x;
  const int lane = tid & 63;
  const int wv   = tid >> 6;
  const int b    = blockIdx.z;
  const int o0   = blockIdx.y * 128;
  const int y0   = blockIdx.x * 2;
  const int wave_m = (wv & 1) * 64;
  const int wn_py  = wv >> 1;         // wave's output row within the 2-row tile

  const u16* xb = xh + (size_t)b * (PW * PW * CIN);
  const u16* wb = wA + (size_t)b * (16 * 9 * COUT * 32);

  f32x4 acc[4][4];
#pragma unroll
  for (int mi = 0; mi < 4; ++mi)
#pragma unroll
    for (int ni = 0; ni < 4; ++ni) acc[mi][ni] = (f32x4){0.f, 0.f, 0.f, 0.f};

  const int l15 = lane & 15;
  const int q   = lane >> 4;          // k-quad 0..3

  for (int ic = 0; ic < 16; ++ic) {
    __syncthreads();                  // prior reads of As/Bs complete
    {
      // stage B window: rows y0..y0+3, cols 0..65, ch ic*32..+32  (1056 x 16B)
      const u16* src0 = xb + (size_t)(y0 * PW) * CIN + ic * 32;
#pragma unroll
      for (int t = 0; t < 4; ++t) {
        const int id = t * 256 + tid;
        const int cc = id >> 2, k = id & 3;
        async16(src0 + (size_t)cc * CIN + k * 8, &Bs[id * 8]);
      }
      if (tid < 32) {
        const int id = 1024 + tid;
        const int cc = id >> 2, k = id & 3;
        async16(src0 + (size_t)cc * CIN + k * 8, &Bs[id * 8]);
      }
      // stage A for tap 0 (contiguous 8 KB)
      const u16* asrc = wb + ((size_t)(ic * 9 + 0) * COUT + o0) * 32;
      async16(asrc + tid * 8, &As[tid * 8]);
      async16(asrc + (256 + tid) * 8, &As[(256 + tid) * 8]);
    }
    __syncthreads();                  // drains vmcnt -> staged data visible

#pragma unroll
    for (int tap = 0; tap < 9; ++tap) {
      if (tap > 0) {
        __syncthreads();              // everyone done reading previous A
        const u16* asrc = wb + ((size_t)(ic * 9 + tap) * COUT + o0) * 32;
        async16(asrc + tid * 8, &As[tid * 8]);
        async16(asrc + (256 + tid) * 8, &As[(256 + tid) * 8]);
        __syncthreads();
      }
      const int ky = tap / 3, kx = tap % 3;

      bf16x8 bfrag[4];
#pragma unroll
      for (int ni = 0; ni < 4; ++ni) {
        const int px = ni * 16 + l15;
        const int rc = (wn_py + ky) * PW + px + kx;
        bfrag[ni] = *(const bf16x8*)&Bs[rc * 32 + q * 8];
      }
#pragma unroll
      for (int mi = 0; mi < 4; ++mi) {
        bf16x8 afrag = *(const bf16x8*)&As[(wave_m + mi * 16 + l15) * 32 + q * 8];
#pragma unroll
        for (int ni = 0; ni < 4; ++ni)
          acc[mi][ni] = __builtin_amdgcn_mfma_f32_16x16x32_bf16(
              afrag, bfrag[ni], acc[mi][ni], 0, 0, 0);
      }
    }
  }

  // epilogue: D mapping col = lane&15 (pixel), row = q*4+reg (o); fp32 out
  const int y = y0 + wn_py;
#pragma unroll
  for (int mi = 0; mi < 4; ++mi) {
#pragma unroll
    for (int r = 0; r < 4; ++r) {
      const int o = o0 + wave_m + mi * 16 + q * 4 + r;
      const float bv = bias[o];
      const size_t obase = (((size_t)b * COUT + o) * HW_ + y) * HW_;
#pragma unroll
      for (int ni = 0; ni < 4; ++ni) {
        const int x = ni * 16 + l15;
        out[obase + x] = acc[mi][ni][r] + bv;
      }
    }
  }
}

// ---------------------------------------------------------------------------
extern "C" void kernel_launch(void* const* d_in, const int* in_sizes, int n_in,
                              void* d_out, int out_size, void* d_ws, size_t ws_size,
                              hipStream_t stream) {
  const float* x    = (const float*)d_in[0];   // [16][512][64][64] fp32
  const float* s    = (const float*)d_in[1];   // [16][512] fp32
  const float* w    = (const float*)d_in[2];   // [512][512][3][3] fp32
  const float* bias = (const float*)d_in[3];   // [512] fp32
  float* out = (float*)d_out;                  // [16][512][64][64] fp32

  u16* xh = (u16*)d_ws;                        // padded NHWC bf16 input
  u16* wA = xh + XH_ELEMS;                     // modulated bf16 weights

  zero_border<<<(B_ * 260 * 64 + 255) / 256, 256, 0, stream>>>(xh);
  transpose_x<<<dim3(8, 64, 16), 256, 0, stream>>>(x, xh);
  mod_weights<<<2048, 256, 0, stream>>>(w, s, wA);
  modconv_mfma<<<dim3(32, 4, 16), 256, 0, stream>>>(xh, wA, bias, out);
}